// Round 4
// baseline (1215.161 us; speedup 1.0000x reference)
//
#include <hip/hip_runtime.h>
#include <cstddef>

#define IMW   96
#define HWSZ  (IMW*IMW)       // 9216
#define CTOT  512
#define CHG   256             // channels per group
#define NBATCH 8
#define ROWP  104             // padded LDS row stride (ushorts)

typedef short  bf16x8  __attribute__((ext_vector_type(8)));
typedef float  f32x4   __attribute__((ext_vector_type(4)));
typedef unsigned short ushort8v __attribute__((ext_vector_type(8)));

__device__ __forceinline__ ushort f2bf(float f) {
    union { float f; unsigned u; } v; v.f = f;
    unsigned r = v.u + 0x7fffu + ((v.u >> 16) & 1u);   // RNE
    return (ushort)(r >> 16);
}
__device__ __forceinline__ float bf2f(ushort u) {
    union { unsigned u; float f; } v; v.u = ((unsigned)u) << 16;
    return v.f;
}

// ---- tiny: convert w_mix (2x256x256 fp32) to bf16 once per launch ----
__global__ __launch_bounds__(256) void wconv_kernel(const float* __restrict__ w,
                                                    ushort* __restrict__ wbf) {
    const int i = blockIdx.x * 256 + threadIdx.x;
    wbf[i] = f2bf(w[i]);
}

// ---------------- kernel 1: grouped 1x1 conv + shuffle, bf16 MFMA ----------------
#define XT_LD 280   // ushort stride: 560 B -> 2-way banks only

__global__ __launch_bounds__(256, 3) void mix_mfma(
    const float* __restrict__ x, const ushort* __restrict__ wbf,
    ushort* __restrict__ h)
{
    const int pt = blockIdx.x * 64;
    const int b  = blockIdx.y >> 1, g = blockIdx.y & 1;
    const float*  xb = x + ((size_t)b * CTOT + (size_t)g * CHG) * HWSZ;
    const ushort* wg = wbf + (size_t)g * CHG * CHG;
    ushort* hb = h + (size_t)b * CTOT * HWSZ;

    __shared__ ushort Xt[64][XT_LD];   // [pixel][k], 35 KB

    const int t  = threadIdx.x;
    const int tq = t & 15;             // pixel quad
    const int tk = t >> 4;             // k-pair selector

    #pragma unroll
    for (int it = 0; it < 8; ++it) {   // covers all k
        const int k = 32 * it + 2 * tk;
        float4 a0 = *(const float4*)&xb[(size_t)k       * HWSZ + pt + 4 * tq];
        float4 a1 = *(const float4*)&xb[(size_t)(k + 1) * HWSZ + pt + 4 * tq];
        *(unsigned*)&Xt[4 * tq + 0][k] = (unsigned)f2bf(a0.x) | ((unsigned)f2bf(a1.x) << 16);
        *(unsigned*)&Xt[4 * tq + 1][k] = (unsigned)f2bf(a0.y) | ((unsigned)f2bf(a1.y) << 16);
        *(unsigned*)&Xt[4 * tq + 2][k] = (unsigned)f2bf(a0.z) | ((unsigned)f2bf(a1.z) << 16);
        *(unsigned*)&Xt[4 * tq + 3][k] = (unsigned)f2bf(a0.w) | ((unsigned)f2bf(a1.w) << 16);
    }
    __syncthreads();

    const int wv  = t >> 6;            // wave -> 64 o-channels
    const int ln  = t & 63;
    const int row = ln & 15;
    const int kb  = ln >> 4;

    f32x4 acc[4][4];
    #pragma unroll
    for (int m = 0; m < 4; ++m)
        #pragma unroll
        for (int n = 0; n < 4; ++n)
            acc[m][n] = (f32x4){0.f, 0.f, 0.f, 0.f};

    #pragma unroll
    for (int ks = 0; ks < 8; ++ks) {
        bf16x8 Xf[4], Wf[4];
        #pragma unroll
        for (int m = 0; m < 4; ++m)    // A operand: X^T[pixel=16m+row][k]
            Xf[m] = *(const bf16x8*)&Xt[16 * m + row][32 * ks + 8 * kb];
        #pragma unroll
        for (int n = 0; n < 4; ++n)    // B operand: W^T[k][o]
            Wf[n] = *(const bf16x8*)&wg[(size_t)(64 * wv + 16 * n + row) * CHG + 32 * ks + 8 * kb];
        #pragma unroll
        for (int m = 0; m < 4; ++m)
            #pragma unroll
            for (int n = 0; n < 4; ++n)
                acc[m][n] = __builtin_amdgcn_mfma_f32_16x16x32_bf16(Xf[m], Wf[n], acc[m][n], 0, 0, 0);
    }

    #pragma unroll
    for (int m = 0; m < 4; ++m) {
        #pragma unroll
        for (int n = 0; n < 4; ++n) {
            const int o = 64 * wv + 16 * n + row;
            const int c = 2 * o + g;                       // channel shuffle folded
            const int p = pt + 16 * m + 4 * kb;
            ushort4 u;
            u.x = f2bf(acc[m][n][0]); u.y = f2bf(acc[m][n][1]);
            u.z = f2bf(acc[m][n][2]); u.w = f2bf(acc[m][n][3]);
            *(ushort4*)&hb[(size_t)c * HWSZ + p] = u;
        }
    }
}

// ------- kernel 2: fused dwconv3x3 + IN + affine + GELU + gate + update -------
// 576 threads: 96 rows x 6 segs x 16 px. h in LDS (bf16); x/prev/gate all fp32
// global+regs. All x reads precede barrier 1 (alias safety); pv completes at
// the reduction barrier (alias safety for t=2).
__global__ __launch_bounds__(576, 5) void plane_kernel(
    const ushort* __restrict__ hmid,
    const float* xcur, const float* xprev,
    const float* __restrict__ wdw,
    const float* __restrict__ gammas, const float* __restrict__ betas,
    const float* __restrict__ alphap, int t,
    float* out)
{
    const int plane = blockIdx.x;          // b*512 + c
    const int c = plane & (CTOT - 1);
    const ushort* hp = hmid + (size_t)plane * HWSZ;
    const float*  xp = xcur + (size_t)plane * HWSZ;
    const float*  pp = xprev + (size_t)plane * HWSZ;
    float* op = out + (size_t)plane * HWSZ;

    __shared__ ushort sh[IMW * ROWP];   // ~20 KB
    __shared__ float  red[32];

    const int tid = threadIdx.x;
    const int r   = tid / 6;            // row 0..95
    const int s6  = tid - r * 6;        // segment 0..5
    const int x0  = s6 * 16;

    // stage h plane into LDS (2 x 16B per thread)
    {
        const uint4* src = (const uint4*)(hp + (size_t)r * IMW);
        uint4* dst = (uint4*)(sh + r * ROWP);
        dst[2 * s6]     = src[2 * s6];
        dst[2 * s6 + 1] = src[2 * s6 + 1];
    }

    // own 16 px of x -> registers (reused for gate, left-window, output)
    float xv[16];
    {
        const float4* s = (const float4*)(xp + (size_t)r * IMW + x0);
        #pragma unroll
        for (int q = 0; q < 4; ++q) {
            float4 v = s[q];
            xv[4 * q] = v.x; xv[4 * q + 1] = v.y; xv[4 * q + 2] = v.z; xv[4 * q + 3] = v.w;
        }
    }

    // gate (exact fp32), fully pre-barrier
    float gate[16];
    #pragma unroll
    for (int half = 0; half < 2; ++half) {
        const int xb = x0 + 8 * half;
        float u[3][8];
        #pragma unroll
        for (int dd = 0; dd < 3; ++dd) {
            int ym = r - (1 << dd); if (ym < 0) ym += IMW;
            const float4* us = (const float4*)(xp + (size_t)ym * IMW + xb);
            float4 a = us[0], b2 = us[1];
            u[dd][0] = a.x;  u[dd][1] = a.y;  u[dd][2] = a.z;  u[dd][3] = a.w;
            u[dd][4] = b2.x; u[dd][5] = b2.y; u[dd][6] = b2.z; u[dd][7] = b2.w;
        }
        float lw[8];
        if (half == 0) {
            const int lx = (x0 == 0) ? (IMW - 8) : (x0 - 8);
            const float4* ls = (const float4*)(xp + (size_t)r * IMW + lx);
            float4 a = ls[0], b2 = ls[1];
            lw[0] = a.x;  lw[1] = a.y;  lw[2] = a.z;  lw[3] = a.w;
            lw[4] = b2.x; lw[5] = b2.y; lw[6] = b2.z; lw[7] = b2.w;
        } else {
            #pragma unroll
            for (int j = 0; j < 8; ++j) lw[j] = xv[j];
        }
        #pragma unroll
        for (int i = 0; i < 8; ++i) {
            const float xvi = xv[8 * half + i];
            float gt = 0.f;
            #pragma unroll
            for (int dd = 0; dd < 3; ++dd) {
                const int d = 1 << dd;
                const float left = (i - d >= 0) ? xv[8 * half + i - d] : lw[8 + i - d];
                gt += fabsf(xvi - u[dd][i]) + fabsf(xvi - left);
            }
            const float eg = __expf(gt * (-1.f / 3.f));
            gate[8 * half + i] = __builtin_amdgcn_rcpf(1.f + eg);
        }
    }

    __syncthreads();   // barrier 1: h staged; ALL xp reads complete (vmcnt drain)

    // issue pv loads early; they fly under the LDS conv work
    float pv[16];
    {
        const float4* s = (const float4*)(pp + (size_t)r * IMW + x0);
        #pragma unroll
        for (int q = 0; q < 4; ++q) {
            float4 v = s[q];
            pv[4 * q] = v.x; pv[4 * q + 1] = v.y; pv[4 * q + 2] = v.z; pv[4 * q + 3] = v.w;
        }
    }

    float w9[9];
    #pragma unroll
    for (int i = 0; i < 9; ++i) w9[i] = wdw[c * 9 + i];

    // depthwise 3x3 from LDS row windows
    float conv[16];
    #pragma unroll
    for (int i = 0; i < 16; ++i) conv[i] = 0.f;
    #pragma unroll
    for (int ky = 0; ky < 3; ++ky) {
        const int yy = r + ky - 1;
        if ((unsigned)yy < IMW) {
            const ushort* rp = sh + yy * ROWP + x0;
            float f[18];
            ushort8v a = *(const ushort8v*)rp;
            ushort8v bq = *(const ushort8v*)(rp + 8);
            f[0]  = (s6 > 0) ? bf2f(rp[-1]) : 0.f;
            f[17] = (s6 < 5) ? bf2f(rp[16]) : 0.f;
            #pragma unroll
            for (int j = 0; j < 8; ++j) { f[1 + j] = bf2f(a[j]); f[9 + j] = bf2f(bq[j]); }
            const float w0 = w9[3 * ky], w1 = w9[3 * ky + 1], w2 = w9[3 * ky + 2];
            #pragma unroll
            for (int i = 0; i < 16; ++i)
                conv[i] = fmaf(w0, f[i], fmaf(w1, f[i + 1], fmaf(w2, f[i + 2], conv[i])));
        }
    }

    float s = 0.f, s2 = 0.f;
    #pragma unroll
    for (int i = 0; i < 16; ++i) { s += conv[i]; s2 = fmaf(conv[i], conv[i], s2); }
    #pragma unroll
    for (int off = 32; off; off >>= 1) {
        s  += __shfl_down(s, off, 64);
        s2 += __shfl_down(s2, off, 64);
    }
    const int wv = tid >> 6;           // 0..8
    if ((tid & 63) == 0) { red[wv] = s; red[16 + wv] = s2; }
    __syncthreads();                   // barrier 2: also guarantees pv complete
    float ssum = 0.f, s2sum = 0.f;
    #pragma unroll
    for (int i = 0; i < 9; ++i) { ssum += red[i]; s2sum += red[16 + i]; }
    const float mu   = ssum * (1.f / HWSZ);
    const float var  = fmaxf(s2sum * (1.f / HWSZ) - mu * mu, 0.f);
    const float rsig = rsqrtf(var + 1e-5f);
    const float ga = gammas[t * CTOT + c] * rsig;
    const float be = betas[t * CTOT + c];
    const float alpha = alphap[0];

    // final: affine + GELU + gated residual update
    #pragma unroll
    for (int half = 0; half < 2; ++half) {
        float o8[8];
        #pragma unroll
        for (int i = 0; i < 8; ++i) {
            const int ii = 8 * half + i;
            const float hn  = fmaf(conv[ii] - mu, ga, be);
            const float z   = 0.7978845608f * fmaf(0.044715f * hn * hn, hn, hn);
            const float e2  = __expf(2.f * z);
            const float th  = 1.f - 2.f * __builtin_amdgcn_rcpf(e2 + 1.f);
            const float gel = 0.5f * hn * (1.f + th);
            o8[i] = fmaf(alpha, xv[ii] - pv[ii], fmaf(gate[ii], gel, xv[ii]));
        }
        const int gbase = r * IMW + x0 + 8 * half;
        *(float4*)(op + gbase)     = make_float4(o8[0], o8[1], o8[2], o8[3]);
        *(float4*)(op + gbase + 4) = make_float4(o8[4], o8[5], o8[6], o8[7]);
    }
}

extern "C" void kernel_launch(void* const* d_in, const int* in_sizes, int n_in,
                              void* d_out, int out_size, void* d_ws, size_t ws_size,
                              hipStream_t stream) {
    const float* x0     = (const float*)d_in[0];
    const float* wmix   = (const float*)d_in[1];
    const float* wdw    = (const float*)d_in[2];
    const float* gammas = (const float*)d_in[3];
    const float* betas  = (const float*)d_in[4];
    const float* alphap = (const float*)d_in[5];

    const size_t NELEM = (size_t)NBATCH * CTOT * HWSZ;   // 37,748,736
    float*  D   = (float*)d_out;                          // x1, x3, x4(final)
    char*   ws  = (char*)d_ws;
    float*  S   = (float*)ws;                             // x2 (fp32)
    ushort* Hb  = (ushort*)(ws + NELEM * 4);              // mix output, bf16
    ushort* Wbf = (ushort*)(ws + NELEM * 4 + NELEM * 2);  // w_mix bf16 (256 KB)

    wconv_kernel<<<512, 256, 0, stream>>>(wmix, Wbf);

    dim3 mgrid(HWSZ / 64, NBATCH * 2);   // (144, 16)
    const int pgrid = NBATCH * CTOT;     // 4096

    // t=0: cur=x0 prev=x0 -> D
    mix_mfma<<<mgrid, 256, 0, stream>>>(x0, Wbf, Hb);
    plane_kernel<<<pgrid, 576, 0, stream>>>(Hb, x0, x0, wdw, gammas, betas, alphap, 0, D);
    // t=1: cur=D prev=x0 -> S
    mix_mfma<<<mgrid, 256, 0, stream>>>(D, Wbf, Hb);
    plane_kernel<<<pgrid, 576, 0, stream>>>(Hb, D, x0, wdw, gammas, betas, alphap, 1, S);
    // t=2: cur=S prev=D -> D (pv reads complete at reduction barrier, stores after)
    mix_mfma<<<mgrid, 256, 0, stream>>>(S, Wbf, Hb);
    plane_kernel<<<pgrid, 576, 0, stream>>>(Hb, S, D, wdw, gammas, betas, alphap, 2, D);
    // t=3: cur=D prev=S -> D (all xp reads complete at barrier 1, stores after)
    mix_mfma<<<mgrid, 256, 0, stream>>>(D, Wbf, Hb);
    plane_kernel<<<pgrid, 576, 0, stream>>>(Hb, D, S, wdw, gammas, betas, alphap, 3, D);
}

// Round 5
// 882.007 us; speedup vs baseline: 1.3777x; 1.3777x over previous
//
#include <hip/hip_runtime.h>
#include <cstddef>

#define IMW   96
#define HWSZ  (IMW*IMW)       // 9216
#define CTOT  512
#define CHG   256             // channels per group
#define NBATCH 8
#define ROWP  104             // padded LDS row stride (ushorts)

typedef short  bf16x8  __attribute__((ext_vector_type(8)));
typedef float  f32x4   __attribute__((ext_vector_type(4)));
typedef unsigned short ushort8v __attribute__((ext_vector_type(8)));

__device__ __forceinline__ ushort f2bf(float f) {
    union { float f; unsigned u; } v; v.f = f;
    unsigned r = v.u + 0x7fffu + ((v.u >> 16) & 1u);   // RNE
    return (ushort)(r >> 16);
}
__device__ __forceinline__ float bf2f(ushort u) {
    union { unsigned u; float f; } v; v.u = ((unsigned)u) << 16;
    return v.f;
}

// ---- tiny: convert w_mix (2x256x256 fp32) to bf16 once per launch ----
__global__ __launch_bounds__(256) void wconv_kernel(const float* __restrict__ w,
                                                    ushort* __restrict__ wbf) {
    const int i = blockIdx.x * 256 + threadIdx.x;
    wbf[i] = f2bf(w[i]);
}

// ---------------- kernel 1: grouped 1x1 conv + shuffle, bf16 MFMA ----------------
#define XT_LD 280   // ushort stride: 560 B -> 2-way banks only

__global__ __launch_bounds__(256, 3) void mix_mfma(
    const float* __restrict__ x, const ushort* __restrict__ wbf,
    ushort* __restrict__ h)
{
    const int pt = blockIdx.x * 64;
    const int b  = blockIdx.y >> 1, g = blockIdx.y & 1;
    const float*  xb = x + ((size_t)b * CTOT + (size_t)g * CHG) * HWSZ;
    const ushort* wg = wbf + (size_t)g * CHG * CHG;
    ushort* hb = h + (size_t)b * CTOT * HWSZ;

    __shared__ ushort Xt[64][XT_LD];   // [pixel][k], 35 KB

    const int t  = threadIdx.x;
    const int tq = t & 15;             // pixel quad
    const int tk = t >> 4;             // k-pair selector

    #pragma unroll
    for (int it = 0; it < 8; ++it) {   // covers all k
        const int k = 32 * it + 2 * tk;
        float4 a0 = *(const float4*)&xb[(size_t)k       * HWSZ + pt + 4 * tq];
        float4 a1 = *(const float4*)&xb[(size_t)(k + 1) * HWSZ + pt + 4 * tq];
        *(unsigned*)&Xt[4 * tq + 0][k] = (unsigned)f2bf(a0.x) | ((unsigned)f2bf(a1.x) << 16);
        *(unsigned*)&Xt[4 * tq + 1][k] = (unsigned)f2bf(a0.y) | ((unsigned)f2bf(a1.y) << 16);
        *(unsigned*)&Xt[4 * tq + 2][k] = (unsigned)f2bf(a0.z) | ((unsigned)f2bf(a1.z) << 16);
        *(unsigned*)&Xt[4 * tq + 3][k] = (unsigned)f2bf(a0.w) | ((unsigned)f2bf(a1.w) << 16);
    }
    __syncthreads();

    const int wv  = t >> 6;            // wave -> 64 o-channels
    const int ln  = t & 63;
    const int row = ln & 15;
    const int kb  = ln >> 4;

    f32x4 acc[4][4];
    #pragma unroll
    for (int m = 0; m < 4; ++m)
        #pragma unroll
        for (int n = 0; n < 4; ++n)
            acc[m][n] = (f32x4){0.f, 0.f, 0.f, 0.f};

    #pragma unroll
    for (int ks = 0; ks < 8; ++ks) {
        bf16x8 Xf[4], Wf[4];
        #pragma unroll
        for (int m = 0; m < 4; ++m)    // A operand: X^T[pixel=16m+row][k]
            Xf[m] = *(const bf16x8*)&Xt[16 * m + row][32 * ks + 8 * kb];
        #pragma unroll
        for (int n = 0; n < 4; ++n)    // B operand: W^T[k][o]
            Wf[n] = *(const bf16x8*)&wg[(size_t)(64 * wv + 16 * n + row) * CHG + 32 * ks + 8 * kb];
        #pragma unroll
        for (int m = 0; m < 4; ++m)
            #pragma unroll
            for (int n = 0; n < 4; ++n)
                acc[m][n] = __builtin_amdgcn_mfma_f32_16x16x32_bf16(Xf[m], Wf[n], acc[m][n], 0, 0, 0);
    }

    #pragma unroll
    for (int m = 0; m < 4; ++m) {
        #pragma unroll
        for (int n = 0; n < 4; ++n) {
            const int o = 64 * wv + 16 * n + row;
            const int c = 2 * o + g;                       // channel shuffle folded
            const int p = pt + 16 * m + 4 * kb;
            ushort4 u;
            u.x = f2bf(acc[m][n][0]); u.y = f2bf(acc[m][n][1]);
            u.z = f2bf(acc[m][n][2]); u.w = f2bf(acc[m][n][3]);
            *(ushort4*)&hb[(size_t)c * HWSZ + p] = u;
        }
    }
}

// ------- kernel 2: fused dwconv3x3 + IN + affine + GELU + gate + update -------
// 576 threads: 96 rows x 6 segs x 16 px. ALL global reads (x, pv, h) at the top,
// pre-barrier (vmcnt drains at barrier 1 -> alias-safe for in-place t=2/t=3).
// Gate neighbors from bf16 LDS; tail is pure registers + stores.
__global__ __launch_bounds__(576, 4) void plane_kernel(
    const ushort* __restrict__ hmid,
    const float* xcur, const float* xprev,
    const float* __restrict__ wdw,
    const float* __restrict__ gammas, const float* __restrict__ betas,
    const float* __restrict__ alphap, int t,
    float* out)
{
    const int plane = blockIdx.x;          // b*512 + c
    const int c = plane & (CTOT - 1);
    const ushort* hp = hmid + (size_t)plane * HWSZ;
    const float*  xp = xcur + (size_t)plane * HWSZ;
    const float*  pp = xprev + (size_t)plane * HWSZ;
    float* op = out + (size_t)plane * HWSZ;

    __shared__ ushort sh[IMW * ROWP];   // ~20 KB h plane (bf16)
    __shared__ ushort sx[IMW * ROWP];   // ~20 KB x plane (bf16, gate neighbors)
    __shared__ float  red[32];

    const int tid = threadIdx.x;
    const int r   = tid / 6;            // row 0..95
    const int s6  = tid - r * 6;        // segment 0..5
    const int x0  = s6 * 16;

    // --- top: issue ALL global reads ---
    float xv[16];
    {
        const float4* s = (const float4*)(xp + (size_t)r * IMW + x0);
        #pragma unroll
        for (int q = 0; q < 4; ++q) {
            float4 v = s[q];
            xv[4 * q] = v.x; xv[4 * q + 1] = v.y; xv[4 * q + 2] = v.z; xv[4 * q + 3] = v.w;
        }
    }
    float pv[16];
    {
        const float4* s = (const float4*)(pp + (size_t)r * IMW + x0);
        #pragma unroll
        for (int q = 0; q < 4; ++q) {
            float4 v = s[q];
            pv[4 * q] = v.x; pv[4 * q + 1] = v.y; pv[4 * q + 2] = v.z; pv[4 * q + 3] = v.w;
        }
    }
    // stage h plane (2 x 16B per thread)
    {
        const uint4* src = (const uint4*)(hp + (size_t)r * IMW);
        uint4* dst = (uint4*)(sh + r * ROWP);
        dst[2 * s6]     = src[2 * s6];
        dst[2 * s6 + 1] = src[2 * s6 + 1];
    }
    // stage x plane bf16 from registers (no second read)
    {
        ushort8v u0, u1;
        #pragma unroll
        for (int j = 0; j < 8; ++j) { u0[j] = f2bf(xv[j]); u1[j] = f2bf(xv[8 + j]); }
        ushort8v* dst = (ushort8v*)(sx + r * ROWP + x0);
        dst[0] = u0; dst[1] = u1;
    }
    __syncthreads();   // barrier 1: LDS staged; all VMEM reads drained

    float w9[9];
    #pragma unroll
    for (int i = 0; i < 9; ++i) w9[i] = wdw[c * 9 + i];

    // depthwise 3x3 from LDS row windows
    float conv[16];
    #pragma unroll
    for (int i = 0; i < 16; ++i) conv[i] = 0.f;
    #pragma unroll
    for (int ky = 0; ky < 3; ++ky) {
        const int yy = r + ky - 1;
        if ((unsigned)yy < IMW) {
            const ushort* rp = sh + yy * ROWP + x0;
            float f[18];
            ushort8v a = *(const ushort8v*)rp;
            ushort8v bq = *(const ushort8v*)(rp + 8);
            f[0]  = (s6 > 0) ? bf2f(rp[-1]) : 0.f;
            f[17] = (s6 < 5) ? bf2f(rp[16]) : 0.f;
            #pragma unroll
            for (int j = 0; j < 8; ++j) { f[1 + j] = bf2f(a[j]); f[9 + j] = bf2f(bq[j]); }
            const float w0 = w9[3 * ky], w1 = w9[3 * ky + 1], w2 = w9[3 * ky + 2];
            #pragma unroll
            for (int i = 0; i < 16; ++i)
                conv[i] = fmaf(w0, f[i], fmaf(w1, f[i + 1], fmaf(w2, f[i + 2], conv[i])));
        }
    }

    // gate: center fp32 (regs), neighbors bf16 (LDS)
    float gate[16];
    {
        float up[3][16];
        #pragma unroll
        for (int dd = 0; dd < 3; ++dd) {
            int ym = r - (1 << dd); if (ym < 0) ym += IMW;
            const ushort8v* vr = (const ushort8v*)(sx + ym * ROWP + x0);
            ushort8v a = vr[0], b2 = vr[1];
            #pragma unroll
            for (int j = 0; j < 8; ++j) { up[dd][j] = bf2f(a[j]); up[dd][8 + j] = bf2f(b2[j]); }
        }
        float wnd[8];   // x_row[(x0-8+j) mod 96]
        {
            const int lx = (x0 == 0) ? (IMW - 8) : (x0 - 8);
            ushort8v h0 = *(const ushort8v*)(sx + r * ROWP + lx);
            #pragma unroll
            for (int j = 0; j < 8; ++j) wnd[j] = bf2f(h0[j]);
        }
        #pragma unroll
        for (int i = 0; i < 16; ++i) {
            const float xvi = xv[i];
            float gt = 0.f;
            #pragma unroll
            for (int dd = 0; dd < 3; ++dd) {
                const int d = 1 << dd;
                const float left = (i - d >= 0) ? xv[i - d] : wnd[8 + i - d];
                gt += fabsf(xvi - up[dd][i]) + fabsf(xvi - left);
            }
            const float eg = __expf(gt * (-1.f / 3.f));
            gate[i] = __builtin_amdgcn_rcpf(1.f + eg);
        }
    }

    // instance-norm moments
    float s = 0.f, s2 = 0.f;
    #pragma unroll
    for (int i = 0; i < 16; ++i) { s += conv[i]; s2 = fmaf(conv[i], conv[i], s2); }
    #pragma unroll
    for (int off = 32; off; off >>= 1) {
        s  += __shfl_down(s, off, 64);
        s2 += __shfl_down(s2, off, 64);
    }
    const int wv = tid >> 6;           // 0..8
    if ((tid & 63) == 0) { red[wv] = s; red[16 + wv] = s2; }
    __syncthreads();                   // barrier 2
    float ssum = 0.f, s2sum = 0.f;
    #pragma unroll
    for (int i = 0; i < 9; ++i) { ssum += red[i]; s2sum += red[16 + i]; }
    const float mu   = ssum * (1.f / HWSZ);
    const float var  = fmaxf(s2sum * (1.f / HWSZ) - mu * mu, 0.f);
    const float rsig = rsqrtf(var + 1e-5f);
    const float ga = gammas[t * CTOT + c] * rsig;
    const float be = betas[t * CTOT + c];
    const float alpha = alphap[0];

    // tail: pure registers -> stores
    #pragma unroll
    for (int half = 0; half < 2; ++half) {
        float o8[8];
        #pragma unroll
        for (int i = 0; i < 8; ++i) {
            const int ii = 8 * half + i;
            const float hn  = fmaf(conv[ii] - mu, ga, be);
            const float z   = 0.7978845608f * fmaf(0.044715f * hn * hn, hn, hn);
            const float e2  = __expf(2.f * z);
            const float th  = 1.f - 2.f * __builtin_amdgcn_rcpf(e2 + 1.f);
            const float gel = 0.5f * hn * (1.f + th);
            o8[i] = fmaf(alpha, xv[ii] - pv[ii], fmaf(gate[ii], gel, xv[ii]));
        }
        const int gbase = r * IMW + x0 + 8 * half;
        *(float4*)(op + gbase)     = make_float4(o8[0], o8[1], o8[2], o8[3]);
        *(float4*)(op + gbase + 4) = make_float4(o8[4], o8[5], o8[6], o8[7]);
    }
}

extern "C" void kernel_launch(void* const* d_in, const int* in_sizes, int n_in,
                              void* d_out, int out_size, void* d_ws, size_t ws_size,
                              hipStream_t stream) {
    const float* x0     = (const float*)d_in[0];
    const float* wmix   = (const float*)d_in[1];
    const float* wdw    = (const float*)d_in[2];
    const float* gammas = (const float*)d_in[3];
    const float* betas  = (const float*)d_in[4];
    const float* alphap = (const float*)d_in[5];

    const size_t NELEM = (size_t)NBATCH * CTOT * HWSZ;   // 37,748,736
    float*  D   = (float*)d_out;                          // x1, x3, x4(final)
    char*   ws  = (char*)d_ws;
    float*  S   = (float*)ws;                             // x2 (fp32)
    ushort* Hb  = (ushort*)(ws + NELEM * 4);              // mix output, bf16
    ushort* Wbf = (ushort*)(ws + NELEM * 4 + NELEM * 2);  // w_mix bf16 (256 KB)

    wconv_kernel<<<512, 256, 0, stream>>>(wmix, Wbf);

    dim3 mgrid(HWSZ / 64, NBATCH * 2);   // (144, 16)
    const int pgrid = NBATCH * CTOT;     // 4096

    // t=0: cur=x0 prev=x0 -> D
    mix_mfma<<<mgrid, 256, 0, stream>>>(x0, Wbf, Hb);
    plane_kernel<<<pgrid, 576, 0, stream>>>(Hb, x0, x0, wdw, gammas, betas, alphap, 0, D);
    // t=1: cur=D prev=x0 -> S
    mix_mfma<<<mgrid, 256, 0, stream>>>(D, Wbf, Hb);
    plane_kernel<<<pgrid, 576, 0, stream>>>(Hb, D, x0, wdw, gammas, betas, alphap, 1, S);
    // t=2: cur=S prev=D -> D (pv read pre-barrier, stores post-barrier)
    mix_mfma<<<mgrid, 256, 0, stream>>>(S, Wbf, Hb);
    plane_kernel<<<pgrid, 576, 0, stream>>>(Hb, S, D, wdw, gammas, betas, alphap, 2, D);
    // t=3: cur=D prev=S -> D (all xp reads pre-barrier, stores post-barrier)
    mix_mfma<<<mgrid, 256, 0, stream>>>(D, Wbf, Hb);
    plane_kernel<<<pgrid, 576, 0, stream>>>(Hb, D, S, wdw, gammas, betas, alphap, 3, D);
}

// Round 6
// 694.340 us; speedup vs baseline: 1.7501x; 1.2703x over previous
//
#include <hip/hip_runtime.h>
#include <cstddef>

#define IMW   96
#define HWSZ  (IMW*IMW)       // 9216
#define CTOT  512
#define CHG   256             // channels per group
#define NBATCH 8
#define ROWP  104             // padded LDS row stride (ushorts)
#define XT_LD 280             // mix LDS stride

typedef short  bf16x8  __attribute__((ext_vector_type(8)));
typedef float  f32x4   __attribute__((ext_vector_type(4)));
typedef unsigned short ushort8v __attribute__((ext_vector_type(8)));

__device__ __forceinline__ ushort f2bf(float f) {
    union { float f; unsigned u; } v; v.f = f;
    unsigned r = v.u + 0x7fffu + ((v.u >> 16) & 1u);   // RNE
    return (ushort)(r >> 16);
}
__device__ __forceinline__ float bf2f(ushort u) {
    union { unsigned u; float f; } v; v.u = ((unsigned)u) << 16;
    return v.f;
}

// ---- tiny: convert w_mix (2x256x256 fp32) to bf16 once per launch ----
__global__ __launch_bounds__(256) void wconv_kernel(const float* __restrict__ w,
                                                    ushort* __restrict__ wbf) {
    const int i = blockIdx.x * 256 + threadIdx.x;
    wbf[i] = f2bf(w[i]);
}

// ---------------- kernel 1: grouped 1x1 conv + shuffle, bf16 MFMA ----------------
// XB=0: x is fp32; XB=1: x is bf16 state.
template<bool XB>
__global__ __launch_bounds__(256, 3) void mix_mfma(
    const void* __restrict__ xin, const ushort* __restrict__ wbf,
    ushort* __restrict__ h)
{
    const int pt = blockIdx.x * 64;
    const int b  = blockIdx.y >> 1, g = blockIdx.y & 1;
    const size_t xoff = ((size_t)b * CTOT + (size_t)g * CHG) * HWSZ;
    const ushort* wg = wbf + (size_t)g * CHG * CHG;
    ushort* hb = h + (size_t)b * CTOT * HWSZ;

    __shared__ ushort Xt[64][XT_LD];   // [pixel][k], 35 KB

    const int t  = threadIdx.x;
    const int tq = t & 15;             // pixel quad
    const int tk = t >> 4;             // k-pair selector

    #pragma unroll
    for (int it = 0; it < 8; ++it) {   // covers all k
        const int k = 32 * it + 2 * tk;
        unsigned u0, u1, u2, u3;
        if constexpr (XB) {
            const ushort* xb = (const ushort*)xin + xoff;
            ushort4 a0 = *(const ushort4*)&xb[(size_t)k       * HWSZ + pt + 4 * tq];
            ushort4 a1 = *(const ushort4*)&xb[(size_t)(k + 1) * HWSZ + pt + 4 * tq];
            u0 = (unsigned)a0.x | ((unsigned)a1.x << 16);
            u1 = (unsigned)a0.y | ((unsigned)a1.y << 16);
            u2 = (unsigned)a0.z | ((unsigned)a1.z << 16);
            u3 = (unsigned)a0.w | ((unsigned)a1.w << 16);
        } else {
            const float* xb = (const float*)xin + xoff;
            float4 a0 = *(const float4*)&xb[(size_t)k       * HWSZ + pt + 4 * tq];
            float4 a1 = *(const float4*)&xb[(size_t)(k + 1) * HWSZ + pt + 4 * tq];
            u0 = (unsigned)f2bf(a0.x) | ((unsigned)f2bf(a1.x) << 16);
            u1 = (unsigned)f2bf(a0.y) | ((unsigned)f2bf(a1.y) << 16);
            u2 = (unsigned)f2bf(a0.z) | ((unsigned)f2bf(a1.z) << 16);
            u3 = (unsigned)f2bf(a0.w) | ((unsigned)f2bf(a1.w) << 16);
        }
        *(unsigned*)&Xt[4 * tq + 0][k] = u0;
        *(unsigned*)&Xt[4 * tq + 1][k] = u1;
        *(unsigned*)&Xt[4 * tq + 2][k] = u2;
        *(unsigned*)&Xt[4 * tq + 3][k] = u3;
    }
    __syncthreads();

    const int wv  = t >> 6;            // wave -> 64 o-channels
    const int ln  = t & 63;
    const int row = ln & 15;
    const int kb  = ln >> 4;

    f32x4 acc[4][4];
    #pragma unroll
    for (int m = 0; m < 4; ++m)
        #pragma unroll
        for (int n = 0; n < 4; ++n)
            acc[m][n] = (f32x4){0.f, 0.f, 0.f, 0.f};

    #pragma unroll
    for (int ks = 0; ks < 8; ++ks) {
        bf16x8 Xf[4], Wf[4];
        #pragma unroll
        for (int m = 0; m < 4; ++m)    // A operand: X^T[pixel=16m+row][k]
            Xf[m] = *(const bf16x8*)&Xt[16 * m + row][32 * ks + 8 * kb];
        #pragma unroll
        for (int n = 0; n < 4; ++n)    // B operand: W^T[k][o]
            Wf[n] = *(const bf16x8*)&wg[(size_t)(64 * wv + 16 * n + row) * CHG + 32 * ks + 8 * kb];
        #pragma unroll
        for (int m = 0; m < 4; ++m)
            #pragma unroll
            for (int n = 0; n < 4; ++n)
                acc[m][n] = __builtin_amdgcn_mfma_f32_16x16x32_bf16(Xf[m], Wf[n], acc[m][n], 0, 0, 0);
    }

    #pragma unroll
    for (int m = 0; m < 4; ++m) {
        #pragma unroll
        for (int n = 0; n < 4; ++n) {
            const int o = 64 * wv + 16 * n + row;
            const int c = 2 * o + g;                       // channel shuffle folded
            const int p = pt + 16 * m + 4 * kb;
            ushort4 u;
            u.x = f2bf(acc[m][n][0]); u.y = f2bf(acc[m][n][1]);
            u.z = f2bf(acc[m][n][2]); u.w = f2bf(acc[m][n][3]);
            *(ushort4*)&hb[(size_t)c * HWSZ + p] = u;
        }
    }
}

// ------- kernel 2: fused dwconv3x3 + IN + affine + GELU + gate + update -------
// 576 threads: 96 rows x 6 segs x 16 px.
// XB: xcur bf16; PB: xprev bf16; OB: out bf16 (else fp32).
// Alias safety (t2: out==pv buffer; t3: out==pv buffer): every global x/pv read
// is the thread's OWN 16 px and the store to those px depends on the loaded
// values -> same-thread read-before-write ordering, no barrier needed.
template<bool XB, bool PB, bool OB>
__global__ __launch_bounds__(576, 5) void plane_kernel(
    const ushort* __restrict__ hmid,
    const void* __restrict__ xcur, const void* __restrict__ xprev,
    const float* __restrict__ wdw,
    const float* __restrict__ gammas, const float* __restrict__ betas,
    const float* __restrict__ alphap, int t,
    void* __restrict__ out)
{
    const int plane = blockIdx.x;          // b*512 + c
    const int c = plane & (CTOT - 1);
    const ushort* hp = hmid + (size_t)plane * HWSZ;

    __shared__ ushort sh[IMW * ROWP];   // ~20 KB h plane (bf16)
    __shared__ ushort sx[IMW * ROWP];   // ~20 KB x plane (bf16)
    __shared__ float  red[32];

    const int tid = threadIdx.x;
    const int r   = tid / 6;            // row 0..95
    const int s6  = tid - r * 6;        // segment 0..5
    const int x0  = s6 * 16;
    const int pix = r * IMW + x0;

    // --- pre-barrier: own-x load (raw), h stage, sx stage ---
    ushort8v xr[2];     // raw bf16 x (XB)
    float4   xf[4];     // raw fp32 x (!XB)
    if constexpr (XB) {
        const ushort8v* s = (const ushort8v*)((const ushort*)xcur + (size_t)plane * HWSZ + pix);
        xr[0] = s[0]; xr[1] = s[1];
    } else {
        const float4* s = (const float4*)((const float*)xcur + (size_t)plane * HWSZ + pix);
        #pragma unroll
        for (int q = 0; q < 4; ++q) xf[q] = s[q];
    }
    // stage h plane (2 x 16B per thread)
    {
        const uint4* src = (const uint4*)(hp + (size_t)r * IMW);
        uint4* dst = (uint4*)(sh + r * ROWP);
        dst[2 * s6]     = src[2 * s6];
        dst[2 * s6 + 1] = src[2 * s6 + 1];
    }
    // stage x plane bf16
    {
        ushort8v* dst = (ushort8v*)(sx + r * ROWP + x0);
        if constexpr (XB) {
            dst[0] = xr[0]; dst[1] = xr[1];          // raw copy, no VALU
        } else {
            ushort8v u0, u1;
            #pragma unroll
            for (int j = 0; j < 4; ++j) {
                u0[j] = f2bf(xf[0][j]); u0[4 + j] = f2bf(xf[1][j]);
                u1[j] = f2bf(xf[2][j]); u1[4 + j] = f2bf(xf[3][j]);
            }
            dst[0] = u0; dst[1] = u1;
        }
    }
    float w9[9];
    #pragma unroll
    for (int i = 0; i < 9; ++i) w9[i] = wdw[c * 9 + i];

    __syncthreads();   // barrier 1: LDS staged

    // issue pv loads now; they fly under the conv work (consumed only in tail)
    ushort8v pr[2];
    float4   pf[4];
    if constexpr (PB) {
        const ushort8v* s = (const ushort8v*)((const ushort*)xprev + (size_t)plane * HWSZ + pix);
        pr[0] = s[0]; pr[1] = s[1];
    } else {
        const float4* s = (const float4*)((const float*)xprev + (size_t)plane * HWSZ + pix);
        #pragma unroll
        for (int q = 0; q < 4; ++q) pf[q] = s[q];
    }

    // depthwise 3x3 from LDS row windows
    float conv[16];
    #pragma unroll
    for (int i = 0; i < 16; ++i) conv[i] = 0.f;
    #pragma unroll
    for (int ky = 0; ky < 3; ++ky) {
        const int yy = r + ky - 1;
        if ((unsigned)yy < IMW) {
            const ushort* rp = sh + yy * ROWP + x0;
            float f[18];
            ushort8v a = *(const ushort8v*)rp;
            ushort8v bq = *(const ushort8v*)(rp + 8);
            f[0]  = (s6 > 0) ? bf2f(rp[-1]) : 0.f;
            f[17] = (s6 < 5) ? bf2f(rp[16]) : 0.f;
            #pragma unroll
            for (int j = 0; j < 8; ++j) { f[1 + j] = bf2f(a[j]); f[9 + j] = bf2f(bq[j]); }
            const float w0 = w9[3 * ky], w1 = w9[3 * ky + 1], w2 = w9[3 * ky + 2];
            #pragma unroll
            for (int i = 0; i < 16; ++i)
                conv[i] = fmaf(w0, f[i], fmaf(w1, f[i + 1], fmaf(w2, f[i + 2], conv[i])));
        }
    }

    // instance-norm moments
    float s = 0.f, s2 = 0.f;
    #pragma unroll
    for (int i = 0; i < 16; ++i) { s += conv[i]; s2 = fmaf(conv[i], conv[i], s2); }
    #pragma unroll
    for (int off = 32; off; off >>= 1) {
        s  += __shfl_down(s, off, 64);
        s2 += __shfl_down(s2, off, 64);
    }
    const int wv = tid >> 6;           // 0..8
    if ((tid & 63) == 0) { red[wv] = s; red[16 + wv] = s2; }
    __syncthreads();                   // barrier 2
    float ssum = 0.f, s2sum = 0.f;
    #pragma unroll
    for (int i = 0; i < 9; ++i) { ssum += red[i]; s2sum += red[16 + i]; }
    const float mu   = ssum * (1.f / HWSZ);
    const float var  = fmaxf(s2sum * (1.f / HWSZ) - mu * mu, 0.f);
    const float rsig = rsqrtf(var + 1e-5f);
    const float ga = gammas[t * CTOT + c] * rsig;
    const float be = betas[t * CTOT + c];
    const float alpha = alphap[0];

    // materialize xv fp32
    float xv[16];
    if constexpr (XB) {
        #pragma unroll
        for (int j = 0; j < 8; ++j) { xv[j] = bf2f(xr[0][j]); xv[8 + j] = bf2f(xr[1][j]); }
    } else {
        #pragma unroll
        for (int q = 0; q < 4; ++q)
            #pragma unroll
            for (int j = 0; j < 4; ++j) xv[4 * q + j] = xf[q][j];
    }

    // tail: gate (sx + regs) + GELU + residual update, per 8-px half
    #pragma unroll
    for (int half = 0; half < 2; ++half) {
        const int xb = x0 + 8 * half;
        float up[3][8];
        #pragma unroll
        for (int dd = 0; dd < 3; ++dd) {
            int ym = r - (1 << dd); if (ym < 0) ym += IMW;
            ushort8v a = *(const ushort8v*)(sx + ym * ROWP + xb);
            #pragma unroll
            for (int j = 0; j < 8; ++j) up[dd][j] = bf2f(a[j]);
        }
        float lw[8];
        if (half == 0) {
            const int lx = (x0 == 0) ? (IMW - 8) : (x0 - 8);
            ushort8v h0 = *(const ushort8v*)(sx + r * ROWP + lx);
            #pragma unroll
            for (int j = 0; j < 8; ++j) lw[j] = bf2f(h0[j]);
        }
        float pvh[8];
        if constexpr (PB) {
            #pragma unroll
            for (int j = 0; j < 8; ++j) pvh[j] = bf2f(pr[half][j]);
        } else {
            #pragma unroll
            for (int j = 0; j < 4; ++j) { pvh[j] = pf[2 * half][j]; pvh[4 + j] = pf[2 * half + 1][j]; }
        }
        float o8[8];
        #pragma unroll
        for (int i = 0; i < 8; ++i) {
            const int ii = 8 * half + i;
            const float xvi = xv[ii];
            float gt = 0.f;
            #pragma unroll
            for (int dd = 0; dd < 3; ++dd) {
                const int d = 1 << dd;
                const float left = (i - d >= 0) ? xv[ii - d]
                                 : (half ? xv[ii - d] : lw[8 + i - d]);
                gt += fabsf(xvi - up[dd][i]) + fabsf(xvi - left);
            }
            const float eg   = __expf(gt * (-1.f / 3.f));
            const float gate = __builtin_amdgcn_rcpf(1.f + eg);
            const float hn  = fmaf(conv[ii] - mu, ga, be);
            const float z   = 0.7978845608f * fmaf(0.044715f * hn * hn, hn, hn);
            const float e2  = __expf(2.f * z);
            const float th  = 1.f - 2.f * __builtin_amdgcn_rcpf(e2 + 1.f);
            const float gel = 0.5f * hn * (1.f + th);
            o8[i] = fmaf(alpha, xvi - pvh[i], fmaf(gate, gel, xvi));
        }
        if constexpr (OB) {
            ushort8v u;
            #pragma unroll
            for (int j = 0; j < 8; ++j) u[j] = f2bf(o8[j]);
            *(ushort8v*)((ushort*)out + (size_t)plane * HWSZ + pix + 8 * half) = u;
        } else {
            float* op = (float*)out + (size_t)plane * HWSZ + pix + 8 * half;
            *(float4*)op       = make_float4(o8[0], o8[1], o8[2], o8[3]);
            *(float4*)(op + 4) = make_float4(o8[4], o8[5], o8[6], o8[7]);
        }
    }
}

extern "C" void kernel_launch(void* const* d_in, const int* in_sizes, int n_in,
                              void* d_out, int out_size, void* d_ws, size_t ws_size,
                              hipStream_t stream) {
    const float* x0     = (const float*)d_in[0];
    const float* wmix   = (const float*)d_in[1];
    const float* wdw    = (const float*)d_in[2];
    const float* gammas = (const float*)d_in[3];
    const float* betas  = (const float*)d_in[4];
    const float* alphap = (const float*)d_in[5];

    const size_t NELEM = (size_t)NBATCH * CTOT * HWSZ;   // 37,748,736
    float*  D   = (float*)d_out;                          // x2 (fp32) then final x4
    char*   ws  = (char*)d_ws;
    ushort* X1b = (ushort*)ws;                            // x1 / x3 (bf16)
    ushort* Hb  = (ushort*)(ws + NELEM * 2);              // mix output, bf16
    ushort* Wbf = (ushort*)(ws + NELEM * 4);              // w_mix bf16 (256 KB)

    wconv_kernel<<<512, 256, 0, stream>>>(wmix, Wbf);

    dim3 mgrid(HWSZ / 64, NBATCH * 2);   // (144, 16)
    const int pgrid = NBATCH * CTOT;     // 4096

    // t=0: cur=x0(f32) prev=x0(f32) -> X1b (bf16)
    mix_mfma<false><<<mgrid, 256, 0, stream>>>(x0, Wbf, Hb);
    plane_kernel<false, false, true><<<pgrid, 576, 0, stream>>>(
        Hb, x0, x0, wdw, gammas, betas, alphap, 0, X1b);
    // t=1: cur=X1b(bf16) prev=x0(f32) -> D (fp32)
    mix_mfma<true><<<mgrid, 256, 0, stream>>>(X1b, Wbf, Hb);
    plane_kernel<true, false, false><<<pgrid, 576, 0, stream>>>(
        Hb, X1b, x0, wdw, gammas, betas, alphap, 1, D);
    // t=2: cur=D(f32) prev=X1b(bf16) -> X1b (bf16; same-thread read-before-write)
    mix_mfma<false><<<mgrid, 256, 0, stream>>>(D, Wbf, Hb);
    plane_kernel<false, true, true><<<pgrid, 576, 0, stream>>>(
        Hb, D, X1b, wdw, gammas, betas, alphap, 2, X1b);
    // t=3: cur=X1b(bf16) prev=D(f32) -> D (fp32; same-thread read-before-write)
    mix_mfma<true><<<mgrid, 256, 0, stream>>>(X1b, Wbf, Hb);
    plane_kernel<true, false, false><<<pgrid, 576, 0, stream>>>(
        Hb, X1b, D, wdw, gammas, betas, alphap, 3, D);
}

// Round 7
// 650.801 us; speedup vs baseline: 1.8672x; 1.0669x over previous
//
#include <hip/hip_runtime.h>
#include <hip/hip_bf16.h>
#include <cstddef>

#define IMW   96
#define HWSZ  (IMW*IMW)       // 9216
#define CTOT  512
#define CHG   256             // channels per group
#define NBATCH 8
#define ROWP  104             // padded LDS row stride (ushorts)
#define XT_LD 280             // mix LDS stride

typedef short  bf16x8  __attribute__((ext_vector_type(8)));
typedef float  f32x4   __attribute__((ext_vector_type(4)));
typedef unsigned short ushort8v __attribute__((ext_vector_type(8)));

// packed f32x2 -> bf16x2 (v_cvt_pk_bf16_f32, RNE) ; lo in bits 0..15
__device__ __forceinline__ unsigned pk2(float lo, float hi) {
    union { __hip_bfloat162 h; unsigned u; } v;
    v.h = __float22bfloat162_rn(make_float2(lo, hi));
    return v.u;
}
__device__ __forceinline__ float bf2f(ushort u) {
    union { unsigned u; float f; } v; v.u = ((unsigned)u) << 16;
    return v.f;
}

// ---- tiny: convert w_mix (2x256x256 fp32) to bf16 once per launch ----
__global__ __launch_bounds__(256) void wconv_kernel(const float* __restrict__ w,
                                                    unsigned* __restrict__ wbf) {
    const int i = blockIdx.x * 256 + threadIdx.x;   // pair index
    wbf[i] = pk2(w[2 * i], w[2 * i + 1]);
}

// ---------------- kernel 1: grouped 1x1 conv + shuffle, bf16 MFMA ----------------
// XB=0: x fp32; XB=1: x bf16 state.
template<bool XB>
__global__ __launch_bounds__(256, 3) void mix_mfma(
    const void* __restrict__ xin, const ushort* __restrict__ wbf,
    ushort* __restrict__ h)
{
    const int pt = blockIdx.x * 64;
    const int b  = blockIdx.y >> 1, g = blockIdx.y & 1;
    const size_t xoff = ((size_t)b * CTOT + (size_t)g * CHG) * HWSZ;
    const ushort* wg = wbf + (size_t)g * CHG * CHG;
    ushort* hb = h + (size_t)b * CTOT * HWSZ;

    __shared__ ushort Xt[64][XT_LD];   // [pixel][k], 35 KB

    const int t  = threadIdx.x;
    const int tq = t & 15;             // pixel quad
    const int tk = t >> 4;             // k-pair selector

    #pragma unroll
    for (int it = 0; it < 8; ++it) {   // covers all k
        const int k = 32 * it + 2 * tk;
        unsigned u0, u1, u2, u3;
        if constexpr (XB) {
            const ushort* xb = (const ushort*)xin + xoff;
            ushort4 a0 = *(const ushort4*)&xb[(size_t)k       * HWSZ + pt + 4 * tq];
            ushort4 a1 = *(const ushort4*)&xb[(size_t)(k + 1) * HWSZ + pt + 4 * tq];
            u0 = (unsigned)a0.x | ((unsigned)a1.x << 16);
            u1 = (unsigned)a0.y | ((unsigned)a1.y << 16);
            u2 = (unsigned)a0.z | ((unsigned)a1.z << 16);
            u3 = (unsigned)a0.w | ((unsigned)a1.w << 16);
        } else {
            const float* xb = (const float*)xin + xoff;
            float4 a0 = *(const float4*)&xb[(size_t)k       * HWSZ + pt + 4 * tq];
            float4 a1 = *(const float4*)&xb[(size_t)(k + 1) * HWSZ + pt + 4 * tq];
            u0 = pk2(a0.x, a1.x);
            u1 = pk2(a0.y, a1.y);
            u2 = pk2(a0.z, a1.z);
            u3 = pk2(a0.w, a1.w);
        }
        *(unsigned*)&Xt[4 * tq + 0][k] = u0;
        *(unsigned*)&Xt[4 * tq + 1][k] = u1;
        *(unsigned*)&Xt[4 * tq + 2][k] = u2;
        *(unsigned*)&Xt[4 * tq + 3][k] = u3;
    }
    __syncthreads();

    const int wv  = t >> 6;            // wave -> 64 o-channels
    const int ln  = t & 63;
    const int row = ln & 15;
    const int kb  = ln >> 4;

    f32x4 acc[4][4];
    #pragma unroll
    for (int m = 0; m < 4; ++m)
        #pragma unroll
        for (int n = 0; n < 4; ++n)
            acc[m][n] = (f32x4){0.f, 0.f, 0.f, 0.f};

    #pragma unroll
    for (int ks = 0; ks < 8; ++ks) {
        bf16x8 Xf[4], Wf[4];
        #pragma unroll
        for (int m = 0; m < 4; ++m)    // A operand: X^T[pixel=16m+row][k]
            Xf[m] = *(const bf16x8*)&Xt[16 * m + row][32 * ks + 8 * kb];
        #pragma unroll
        for (int n = 0; n < 4; ++n)    // B operand: W^T[k][o]
            Wf[n] = *(const bf16x8*)&wg[(size_t)(64 * wv + 16 * n + row) * CHG + 32 * ks + 8 * kb];
        #pragma unroll
        for (int m = 0; m < 4; ++m)
            #pragma unroll
            for (int n = 0; n < 4; ++n)
                acc[m][n] = __builtin_amdgcn_mfma_f32_16x16x32_bf16(Xf[m], Wf[n], acc[m][n], 0, 0, 0);
    }

    #pragma unroll
    for (int m = 0; m < 4; ++m) {
        #pragma unroll
        for (int n = 0; n < 4; ++n) {
            const int o = 64 * wv + 16 * n + row;
            const int c = 2 * o + g;                       // channel shuffle folded
            const int p = pt + 16 * m + 4 * kb;
            uint2 u;
            u.x = pk2(acc[m][n][0], acc[m][n][1]);
            u.y = pk2(acc[m][n][2], acc[m][n][3]);
            *(uint2*)&hb[(size_t)c * HWSZ + p] = u;
        }
    }
}

// ------- kernel 2: fused dwconv3x3 + IN + affine + GELU + gate + update -------
// 576 threads: 96 rows x 6 segs x 16 px.
// XB: cur bf16; PB: prev bf16; EQ: prev==cur (skip load); OB: out bf16.
// Alias safety (t2: out==prev buffer): pv read is the thread's OWN px and the
// store value depends on it -> same-thread read-before-write.
template<bool XB, bool PB, bool EQ, bool OB>
__global__ __launch_bounds__(576, 4) void plane_kernel(
    const ushort* __restrict__ hmid,
    const void* __restrict__ xcur, const void* __restrict__ xprev,
    const float* __restrict__ wdw,
    const float* __restrict__ gammas, const float* __restrict__ betas,
    const float* __restrict__ alphap, int t,
    void* __restrict__ out)
{
    const int plane = blockIdx.x;          // b*512 + c
    const int c = plane & (CTOT - 1);
    const ushort* hp = hmid + (size_t)plane * HWSZ;

    __shared__ ushort sh[IMW * ROWP];   // ~20 KB h plane (bf16)
    __shared__ ushort sx[IMW * ROWP];   // ~20 KB x plane (bf16)
    __shared__ float  red[32];

    const int tid = threadIdx.x;
    const int r   = tid / 6;            // row 0..95
    const int s6  = tid - r * 6;        // segment 0..5
    const int x0  = s6 * 16;
    const int pix = r * IMW + x0;

    // --- pre-barrier: own-x load (packed), h stage, sx stage ---
    ushort8v xr[2];     // raw bf16 x (XB)
    float4   xf[4];     // raw fp32 x (!XB)
    if constexpr (XB) {
        const ushort8v* s = (const ushort8v*)((const ushort*)xcur + (size_t)plane * HWSZ + pix);
        xr[0] = s[0]; xr[1] = s[1];
    } else {
        const float4* s = (const float4*)((const float*)xcur + (size_t)plane * HWSZ + pix);
        #pragma unroll
        for (int q = 0; q < 4; ++q) xf[q] = s[q];
    }
    // stage h plane (2 x 16B per thread)
    {
        const uint4* src = (const uint4*)(hp + (size_t)r * IMW);
        uint4* dst = (uint4*)(sh + r * ROWP);
        dst[2 * s6]     = src[2 * s6];
        dst[2 * s6 + 1] = src[2 * s6 + 1];
    }
    // stage x plane bf16
    {
        if constexpr (XB) {
            ushort8v* dst = (ushort8v*)(sx + r * ROWP + x0);
            dst[0] = xr[0]; dst[1] = xr[1];          // raw copy, no VALU
        } else {
            uint4* dst = (uint4*)(sx + r * ROWP + x0);
            dst[0] = make_uint4(pk2(xf[0].x, xf[0].y), pk2(xf[0].z, xf[0].w),
                                pk2(xf[1].x, xf[1].y), pk2(xf[1].z, xf[1].w));
            dst[1] = make_uint4(pk2(xf[2].x, xf[2].y), pk2(xf[2].z, xf[2].w),
                                pk2(xf[3].x, xf[3].y), pk2(xf[3].z, xf[3].w));
        }
    }
    float w9[9];
    #pragma unroll
    for (int i = 0; i < 9; ++i) w9[i] = wdw[c * 9 + i];

    __syncthreads();   // barrier 1: LDS staged

    // issue pv loads now (packed regs); consumed only in tail
    ushort8v pr[2];
    float4   pf[4];
    if constexpr (!EQ) {
        if constexpr (PB) {
            const ushort8v* s = (const ushort8v*)((const ushort*)xprev + (size_t)plane * HWSZ + pix);
            pr[0] = s[0]; pr[1] = s[1];
        } else {
            const float4* s = (const float4*)((const float*)xprev + (size_t)plane * HWSZ + pix);
            #pragma unroll
            for (int q = 0; q < 4; ++q) pf[q] = s[q];
        }
    }

    // depthwise 3x3 from LDS row windows
    float conv[16];
    #pragma unroll
    for (int i = 0; i < 16; ++i) conv[i] = 0.f;
    #pragma unroll
    for (int ky = 0; ky < 3; ++ky) {
        const int yy = r + ky - 1;
        if ((unsigned)yy < IMW) {
            const ushort* rp = sh + yy * ROWP + x0;
            float f[18];
            ushort8v a = *(const ushort8v*)rp;
            ushort8v bq = *(const ushort8v*)(rp + 8);
            f[0]  = (s6 > 0) ? bf2f(rp[-1]) : 0.f;
            f[17] = (s6 < 5) ? bf2f(rp[16]) : 0.f;
            #pragma unroll
            for (int j = 0; j < 8; ++j) { f[1 + j] = bf2f(a[j]); f[9 + j] = bf2f(bq[j]); }
            const float w0 = w9[3 * ky], w1 = w9[3 * ky + 1], w2 = w9[3 * ky + 2];
            #pragma unroll
            for (int i = 0; i < 16; ++i)
                conv[i] = fmaf(w0, f[i], fmaf(w1, f[i + 1], fmaf(w2, f[i + 2], conv[i])));
        }
    }

    // materialize xv fp32
    float xv[16];
    if constexpr (XB) {
        #pragma unroll
        for (int j = 0; j < 8; ++j) { xv[j] = bf2f(xr[0][j]); xv[8 + j] = bf2f(xr[1][j]); }
    } else {
        #pragma unroll
        for (int q = 0; q < 4; ++q)
            #pragma unroll
            for (int j = 0; j < 4; ++j) xv[4 * q + j] = xf[q][j];
    }

    // gate accumulation gt (before the reduction barrier -> overlaps the wait)
    float gt[16];
    #pragma unroll
    for (int half = 0; half < 2; ++half) {
        const int xb = x0 + 8 * half;
        float up[3][8];
        #pragma unroll
        for (int dd = 0; dd < 3; ++dd) {
            int ym = r - (1 << dd); if (ym < 0) ym += IMW;
            ushort8v a = *(const ushort8v*)(sx + ym * ROWP + xb);
            #pragma unroll
            for (int j = 0; j < 8; ++j) up[dd][j] = bf2f(a[j]);
        }
        float lw[8];
        if (half == 0) {
            const int lx = (x0 == 0) ? (IMW - 8) : (x0 - 8);
            ushort8v h0 = *(const ushort8v*)(sx + r * ROWP + lx);
            #pragma unroll
            for (int j = 0; j < 8; ++j) lw[j] = bf2f(h0[j]);
        }
        #pragma unroll
        for (int i = 0; i < 8; ++i) {
            const int ii = 8 * half + i;
            const float xvi = xv[ii];
            float g = 0.f;
            #pragma unroll
            for (int dd = 0; dd < 3; ++dd) {
                const int d = 1 << dd;
                const float left = (i - d >= 0) ? xv[ii - d]
                                 : (half ? xv[ii - d] : lw[8 + i - d]);
                g += fabsf(xvi - up[dd][i]) + fabsf(xvi - left);
            }
            gt[ii] = g;
        }
    }

    // instance-norm moments
    float s = 0.f, s2 = 0.f;
    #pragma unroll
    for (int i = 0; i < 16; ++i) { s += conv[i]; s2 = fmaf(conv[i], conv[i], s2); }
    #pragma unroll
    for (int off = 32; off; off >>= 1) {
        s  += __shfl_down(s, off, 64);
        s2 += __shfl_down(s2, off, 64);
    }
    const int wv = tid >> 6;           // 0..8
    if ((tid & 63) == 0) { red[wv] = s; red[16 + wv] = s2; }
    __syncthreads();                   // barrier 2
    float ssum = 0.f, s2sum = 0.f;
    #pragma unroll
    for (int i = 0; i < 9; ++i) { ssum += red[i]; s2sum += red[16 + i]; }
    const float mu   = ssum * (1.f / HWSZ);
    const float var  = fmaxf(s2sum * (1.f / HWSZ) - mu * mu, 0.f);
    const float rsig = rsqrtf(var + 1e-5f);
    const float ga = gammas[t * CTOT + c] * rsig;
    const float be = betas[t * CTOT + c];
    const float alpha = alphap[0];

    // tail: gate finish + GELU + residual update
    #pragma unroll
    for (int half = 0; half < 2; ++half) {
        float pvh[8];
        if constexpr (EQ) {
            #pragma unroll
            for (int j = 0; j < 8; ++j) pvh[j] = xv[8 * half + j];
        } else if constexpr (PB) {
            #pragma unroll
            for (int j = 0; j < 8; ++j) pvh[j] = bf2f(pr[half][j]);
        } else {
            #pragma unroll
            for (int j = 0; j < 4; ++j) { pvh[j] = pf[2 * half][j]; pvh[4 + j] = pf[2 * half + 1][j]; }
        }
        float o8[8];
        #pragma unroll
        for (int i = 0; i < 8; ++i) {
            const int ii = 8 * half + i;
            const float xvi = xv[ii];
            const float eg   = __expf(gt[ii] * (-1.f / 3.f));
            const float gate = __builtin_amdgcn_rcpf(1.f + eg);
            const float hn  = fmaf(conv[ii] - mu, ga, be);
            const float z   = 0.7978845608f * fmaf(0.044715f * hn * hn, hn, hn);
            const float e2  = __expf(2.f * z);
            const float th  = 1.f - 2.f * __builtin_amdgcn_rcpf(e2 + 1.f);
            const float gel = 0.5f * hn * (1.f + th);
            o8[i] = fmaf(alpha, xvi - pvh[i], fmaf(gate, gel, xvi));
        }
        if constexpr (OB) {
            uint4 u = make_uint4(pk2(o8[0], o8[1]), pk2(o8[2], o8[3]),
                                 pk2(o8[4], o8[5]), pk2(o8[6], o8[7]));
            *(uint4*)((ushort*)out + (size_t)plane * HWSZ + pix + 8 * half) = u;
        } else {
            float* op = (float*)out + (size_t)plane * HWSZ + pix + 8 * half;
            *(float4*)op       = make_float4(o8[0], o8[1], o8[2], o8[3]);
            *(float4*)(op + 4) = make_float4(o8[4], o8[5], o8[6], o8[7]);
        }
    }
}

extern "C" void kernel_launch(void* const* d_in, const int* in_sizes, int n_in,
                              void* d_out, int out_size, void* d_ws, size_t ws_size,
                              hipStream_t stream) {
    const float* x0     = (const float*)d_in[0];
    const float* wmix   = (const float*)d_in[1];
    const float* wdw    = (const float*)d_in[2];
    const float* gammas = (const float*)d_in[3];
    const float* betas  = (const float*)d_in[4];
    const float* alphap = (const float*)d_in[5];

    const size_t NELEM = (size_t)NBATCH * CTOT * HWSZ;   // 37,748,736
    float*  D   = (float*)d_out;                          // final x4 (fp32)
    char*   ws  = (char*)d_ws;
    ushort* X1b = (ushort*)ws;                            // x1, then x3 (bf16)
    ushort* X2b = (ushort*)(ws + NELEM * 2);              // x2 (bf16)
    ushort* Hb  = (ushort*)(ws + NELEM * 4);              // mix output (bf16)
    ushort* Wbf = (ushort*)(ws + NELEM * 6);              // w_mix bf16 (256 KB)

    wconv_kernel<<<256, 256, 0, stream>>>(wmix, (unsigned*)Wbf);

    dim3 mgrid(HWSZ / 64, NBATCH * 2);   // (144, 16)
    const int pgrid = NBATCH * CTOT;     // 4096

    // t=0: cur=prev=x0 (fp32) -> X1b (bf16)
    mix_mfma<false><<<mgrid, 256, 0, stream>>>(x0, Wbf, Hb);
    plane_kernel<false, false, true, true><<<pgrid, 576, 0, stream>>>(
        Hb, x0, x0, wdw, gammas, betas, alphap, 0, X1b);
    // t=1: cur=X1b prev=x0 (fp32) -> X2b (bf16)
    mix_mfma<true><<<mgrid, 256, 0, stream>>>(X1b, Wbf, Hb);
    plane_kernel<true, false, false, true><<<pgrid, 576, 0, stream>>>(
        Hb, X1b, x0, wdw, gammas, betas, alphap, 1, X2b);
    // t=2: cur=X2b prev=X1b -> X1b (same-thread read-before-write alias)
    mix_mfma<true><<<mgrid, 256, 0, stream>>>(X2b, Wbf, Hb);
    plane_kernel<true, true, false, true><<<pgrid, 576, 0, stream>>>(
        Hb, X2b, X1b, wdw, gammas, betas, alphap, 2, X1b);
    // t=3: cur=X1b(x3) prev=X2b -> D (fp32 final)
    mix_mfma<true><<<mgrid, 256, 0, stream>>>(X1b, Wbf, Hb);
    plane_kernel<true, true, false, false><<<pgrid, 576, 0, stream>>>(
        Hb, X1b, X2b, wdw, gammas, betas, alphap, 3, D);
}